// Round 6
// baseline (20840.492 us; speedup 1.0000x reference)
//
#include <hip/hip_runtime.h>
#include <cstdint>

// VAN checkerboard sampler, LEVEL=0, B=4096, L=16, H=32, K=5.
// Maintained-a2 incremental design with ~50% block-uniform skip.
// R6: phase-B cross-wave reduction via LDS atomicAdd (ds_add_f32) directly into
// s_a2 -> update step has 3 barriers (was 8), skip step 1; staging buffer gone
// (LDS 69KB -> 53KB, 3 blocks/CU by LDS). shfl ic-pair merge kept deterministic;
// only the 8-way wave sum is order-varying (~1 ulp in a2, same class as the
// summation-order changes that passed R1-R5 with absmax 0).
// s_c3 parity double-buffer closes the skip-path read/write race w/o a barrier.

struct U2 { uint32_t x, y; };

// JAX Threefry-2x32 (20 rounds) — verified bit-exact in rounds 1-5
__device__ __forceinline__ U2 tf2x32(uint32_t k0, uint32_t k1, uint32_t x0, uint32_t x1) {
  uint32_t k2 = k0 ^ k1 ^ 0x1BD11BDAu;
#define TFROT(r) { x0 += x1; x1 = (x1 << (r)) | (x1 >> (32 - (r))); x1 ^= x0; }
  x0 += k0; x1 += k1;
  TFROT(13) TFROT(15) TFROT(26) TFROT(6)
  x0 += k1; x1 += k2 + 1u;
  TFROT(17) TFROT(29) TFROT(16) TFROT(24)
  x0 += k2; x1 += k0 + 2u;
  TFROT(13) TFROT(15) TFROT(26) TFROT(6)
  x0 += k0; x1 += k1 + 3u;
  TFROT(17) TFROT(29) TFROT(16) TFROT(24)
  x0 += k1; x1 += k2 + 4u;
  TFROT(13) TFROT(15) TFROT(26) TFROT(6)
  x0 += k2; x1 += k0 + 5u;
#undef TFROT
  return {x0, x1};
}

__device__ __forceinline__ float lrelu(float v) { return fmaxf(v, 0.1f * v); }

// phase-B partial: 5x5 delta_h1(ic) (*) w2 -> 3 output rows (chunk CCH), acc[27]
template<int CCH>
__device__ __forceinline__ void pb_accum(const float (&w2)[25], const float* h1d_ic,
                                         float (&acc)[27]) {
  #pragma unroll
  for (int dyp = 0; dyp < 5; ++dyp) {
    if (dyp + 4 < 3 * CCH || dyp + 4 > 3 * CCH + 6) continue;   // compile-time fold
    float h[5];
    #pragma unroll
    for (int dxp = 0; dxp < 5; ++dxp) h[dxp] = h1d_ic[(dyp * 5 + dxp) * 32];
    #pragma unroll
    for (int u2 = 0; u2 < 3; ++u2) {
      const int ky = dyp + 4 - 3 * CCH - u2;
      if (ky < 0 || ky > 4) continue;                           // compile-time fold
      #pragma unroll
      for (int kx = 0; kx < 5; ++kx) {
        const float w = w2[ky * 5 + kx];
        #pragma unroll
        for (int dxp = 0; dxp < 5; ++dxp)
          acc[u2 * 9 + dxp - kx + 4] = fmaf(h[dxp], w, acc[u2 * 9 + dxp - kx + 4]);
      }
    }
  }
}

// phase-B chunk: compute partials, shfl ic-pair merge, atomic-add into s_a2
template<int CCH>
__device__ __forceinline__ void pb_chunk(const float (&w2a)[25], const float (&w2b)[25],
                                         int icp, const float* s_h1d, float* s_a2,
                                         int lane, int i, int j) {
  float acc[27];
  #pragma unroll
  for (int q = 0; q < 27; ++q) acc[q] = 0.f;
  pb_accum<CCH>(w2a, s_h1d + icp, acc);
  pb_accum<CCH>(w2b, s_h1d + icp + 16, acc);
  #pragma unroll
  for (int q = 0; q < 27; ++q) acc[q] += __shfl_xor(acc[q], 32, 64);
  if (lane < 32) {
    #pragma unroll
    for (int q = 0; q < 27; ++q) {
      const int u2 = q / 9, V = q - 9 * u2;                     // compile-time (q unrolled)
      int idx = (((i - 4 + 3 * CCH + u2) & 15) * 16 + ((j - 4 + V) & 15)) * 32 + lane;
      atomicAdd(&s_a2[idx], acc[q]);
    }
  }
}

// init conv2 partial for one a2 row, one ic: 16 columns
__device__ __forceinline__ void init_conv2_half(const float (&w2)[25], int icc,
                                                const float* s_win, float (&acc)[16]) {
  #pragma unroll
  for (int ky = 0; ky < 5; ++ky) {
    float h[16];
    #pragma unroll
    for (int col = 0; col < 16; ++col) h[col] = s_win[ky * 512 + col * 32 + icc];
    #pragma unroll
    for (int kx = 0; kx < 5; ++kx) {
      const float w = w2[ky * 5 + kx];
      #pragma unroll
      for (int X = 0; X < 16; ++X)
        acc[X] = fmaf(h[(X + kx - 2) & 15], w, acc[X]);
    }
  }
}

__launch_bounds__(512, 2)
__global__ void van_kernel(const float* __restrict__ gx,
                           const float* __restrict__ gw1, const float* __restrict__ gb1,
                           const float* __restrict__ gw2, const float* __restrict__ gb2,
                           const float* __restrict__ gw3, const float* __restrict__ gb3,
                           float* __restrict__ out, int B) {
  __shared__ __align__(16) float s_xf[784];        // x with +/-6 circular halo (28x28)
  __shared__ __align__(16) float s_w1[800];
  __shared__ float s_b1[32], s_b2[32];
  __shared__ float s_u[64];
  __shared__ float s_c3[2][8];                     // parity double-buffer
  __shared__ __align__(16) float s_h1d[800];       // delta_h1: [pos25][ic32]
  __shared__ __align__(16) float s_a2[8192];       // a2 (+b2): [(row*16+col)*32+oc]
  __shared__ __align__(16) float s_win[2560];      // init 5-row h1 window

  const int tid  = threadIdx.x;
  const int bg   = blockIdx.x;
  const int lane = tid & 63;
  const int wv   = tid >> 6;
  const int oc   = tid & 31;   // conv2 out-channel
  const int icp  = tid >> 5;   // conv2 in-channel pair base: handles icp and icp+16

  // ---------------- setup ----------------
  const float b3v = gb3[0];
  float w2a[25], w2b[25];
  {
    const float* pa = gw2 + (oc * 32 + icp) * 25;         // w2[oc][icp][.]
    const float* pb = gw2 + (oc * 32 + icp + 16) * 25;    // w2[oc][icp+16][.]
    #pragma unroll
    for (int k = 0; k < 25; ++k) { w2a[k] = pa[k]; w2b[k] = pb[k]; }
  }
  float w3r1 = gw3[(tid & 31) * 25 + (tid >> 5)];         // entry e=tid: w3[oc][p]
  float w3r2 = 0.f;
  if (tid < 288) {
    int e = tid + 512;
    w3r2 = gw3[(e & 31) * 25 + (e >> 5)];
  }
  s_w1[tid] = gw1[tid];
  if (tid < 288) s_w1[tid + 512] = gw1[tid + 512];
  if (tid < 32)  { s_b1[tid] = gb1[tid]; s_b2[tid] = gb2[tid]; }
  {
    int rr = tid / 28, cc = tid - rr * 28;
    s_xf[tid] = gx[bg * 256 + ((rr - 6) & 15) * 16 + ((cc - 6) & 15)];
    if (tid < 272) {
      int t2 = tid + 512;
      int r2 = t2 / 28, c2 = t2 - r2 * 28;
      s_xf[t2] = gx[bg * 256 + ((r2 - 6) & 15) * 16 + ((c2 - 6) & 15)];
    }
  }
  if (tid < 64) {
    U2 key = tf2x32(0u, 42u, 0u, (uint32_t)tid);
    U2 tt  = tf2x32(key.x, key.y, 0u, (uint32_t)bg);
    uint32_t bits = tt.x ^ tt.y;
    s_u[tid] = __uint_as_float(0x3F800000u | (bits >> 9)) - 1.0f;
  }
  // a2 pre-fill with b2 (atomic adds accumulate on top)
  #pragma unroll
  for (int k = 0; k < 16; ++k) s_a2[k * 512 + tid] = gb2[tid & 31];
  __syncthreads();

  // ---------------- init: a2 field row by row (h1 window + atomic adds) ----------------
  #pragma unroll 1
  for (int t = 0; t < 16; ++t) {
    // 5-row h1 window: slot r5 holds field row (t+r5-2)&15; thread = (col,ic)
    {
      const int colW = tid >> 5, icW = tid & 31;
      const float* wp = &s_w1[icW * 25];
      const float bb = s_b1[icW];
      #pragma unroll
      for (int r5 = 0; r5 < 5; ++r5) {
        int f = (t + r5 - 2) & 15;
        float a = bb;
        #pragma unroll
        for (int ky = 0; ky < 5; ++ky)
          #pragma unroll
          for (int kx = 0; kx < 5; ++kx)
            a = fmaf(s_xf[(f + 4 + ky) * 28 + colW + 4 + kx], wp[ky * 5 + kx], a);
        s_win[r5 * 512 + tid] = lrelu(a);
      }
    }
    __syncthreads();                       // window ready
    float acc[16];
    #pragma unroll
    for (int X = 0; X < 16; ++X) acc[X] = 0.f;
    init_conv2_half(w2a, icp, s_win, acc);
    init_conv2_half(w2b, icp + 16, s_win, acc);
    #pragma unroll
    for (int X = 0; X < 16; ++X) acc[X] += __shfl_xor(acc[X], 32, 64);
    if (lane < 32) {
      #pragma unroll
      for (int X = 0; X < 16; ++X) atomicAdd(&s_a2[t * 512 + X * 32 + lane], acc[X]);
    }
    __syncthreads();                       // window consumed + row complete
  }

  // ---------------- main autoregressive loop ----------------
  float logq = 0.f;
  #pragma unroll 1
  for (int s = 0; s < 64; ++s) {
    const int i = 2 * (s >> 3) + 1;
    const int j = 2 * (s & 7) + 1;
    const int par = s & 1;

    // ---- conv3 from maintained a2 (800 terms over 512 threads) ----
    float v3;
    {
      int p1 = tid >> 5, o1 = tid & 31;
      int dy = p1 / 5, dx = p1 - 5 * dy;
      int idx = (((i + dy - 2) & 15) * 16 + ((j + dx - 2) & 15)) * 32 + o1;
      v3 = lrelu(s_a2[idx]) * w3r1;
      if (tid < 288) {
        int e = tid + 512, p2 = e >> 5, o2 = e & 31;
        int dy2 = p2 / 5, dx2 = p2 - 5 * dy2;
        int idx2 = (((i + dy2 - 2) & 15) * 16 + ((j + dx2 - 2) & 15)) * 32 + o2;
        v3 = fmaf(lrelu(s_a2[idx2]), w3r2, v3);
      }
    }
    #pragma unroll
    for (int m = 32; m >= 1; m >>= 1) v3 += __shfl_xor(v3, m, 64);
    if (lane == 0) s_c3[par][wv] = v3;
    __syncthreads();                                   // barrier 1: logit parts ready

    // ---- sample (all threads, redundant & identical) ----
    float logit = b3v;
    #pragma unroll
    for (int v = 0; v < 8; ++v) logit += s_c3[par][v];
    const float pr   = 1.f / (1.f + expf(-logit));
    const float u    = s_u[s];
    const float samp = (u < pr) ? 1.f : -1.f;
    const float xold = s_xf[(i + 6) * 28 + (j + 6)];
    logq += (samp > 0.f) ? logf(pr + 1e-7f) : logf(1.f - pr + 1e-7f);

    if (samp == xold) continue;                        // block-uniform skip (~50%)

    // ---- phase A: delta_h1 at 25 positions x 32 ic (800 entries) ----
    {
      const float delta = samp - xold;                 // +/-2
      #pragma unroll
      for (int rep = 0; rep < 2; ++rep) {
        int e = tid + rep * 512;
        if (rep == 1 && tid >= 288) break;
        int p = e >> 5, icA = e & 31;
        int dyq = p / 5, dxq = p - 5 * dyq;
        const float* wp = &s_w1[icA * 25];
        float a1v = s_b1[icA];
        int base = (i + dyq + 2) * 28 + (j + dxq + 2);
        #pragma unroll
        for (int ky = 0; ky < 5; ++ky)
          #pragma unroll
          for (int kx = 0; kx < 5; ++kx)
            a1v = fmaf(s_xf[base + ky * 28 + kx], wp[ky * 5 + kx], a1v);
        float a1n = fmaf(delta, wp[(4 - dyq) * 5 + (4 - dxq)], a1v);
        s_h1d[p * 32 + icA] = lrelu(a1n) - lrelu(a1v);
      }
    }
    __syncthreads();                                   // barrier 2: h1d ready

    if (tid == 511) {                                  // update x halo copies
      int r1 = i + 6, c1 = j + 6;
      int r2 = (i < 6) ? i + 22 : ((i >= 10) ? i - 10 : r1);
      int c2 = (j < 6) ? j + 22 : ((j >= 10) ? j - 10 : c1);
      s_xf[r1 * 28 + c1] = samp; s_xf[r1 * 28 + c2] = samp;
      s_xf[r2 * 28 + c1] = samp; s_xf[r2 * 28 + c2] = samp;
    }

    // ---- phase B: 5x5 delta_h1 (*) w2 -> 9x9 a2 atomic update ----
    pb_chunk<0>(w2a, w2b, icp, s_h1d, s_a2, lane, i, j);
    pb_chunk<1>(w2a, w2b, icp, s_h1d, s_a2, lane, i, j);
    pb_chunk<2>(w2a, w2b, icp, s_h1d, s_a2, lane, i, j);
    __syncthreads();                                   // barrier 3: a2 consistent
  }

  // ---------------- output ----------------
  if (tid < 256)
    out[bg * 256 + tid] = s_xf[((tid >> 4) + 6) * 28 + (tid & 15) + 6];
  if (tid == 0)
    out[B * 256 + bg] = logq;
}

extern "C" void kernel_launch(void* const* d_in, const int* in_sizes, int n_in,
                              void* d_out, int out_size, void* d_ws, size_t ws_size,
                              hipStream_t stream) {
  const float* gx  = (const float*)d_in[0];
  const float* gw1 = (const float*)d_in[1];
  const float* gb1 = (const float*)d_in[2];
  const float* gw2 = (const float*)d_in[3];
  const float* gb2 = (const float*)d_in[4];
  const float* gw3 = (const float*)d_in[5];
  const float* gb3 = (const float*)d_in[6];
  float* out = (float*)d_out;
  const int B = in_sizes[0] / 256;

  hipLaunchKernelGGL(van_kernel, dim3(B), dim3(512), 0, stream,
                     gx, gw1, gb1, gw2, gb2, gw3, gb3, out, B);
}